// Round 2
// baseline (5347.678 us; speedup 1.0000x reference)
//
#include <hip/hip_runtime.h>
#include <math.h>

#define AVGD 2.833213344056216f  // log(17.0)

// monotone float<->uint map: order-preserving, so integer atomicMax/Min work
__device__ __forceinline__ unsigned enc(float f) {
  unsigned b = __float_as_uint(f);
  return (b & 0x80000000u) ? ~b : (b | 0x80000000u);
}
__device__ __forceinline__ float dec(unsigned u) {
  unsigned b = (u & 0x80000000u) ? (u ^ 0x80000000u) : ~u;
  return __uint_as_float(b);
}

// ---------------- edge kernel: aggregate w = h_in[src] + ef into per-node stats ----------------
// wave handles 4 edges: lane -> (edge sub = lane>>4, feature base = (lane&15)*4), float4 I/O.
// All atomics are fire-and-forget (no return value used) -> no latency on critical path.
__global__ __launch_bounds__(256) void k_edge(
    const float* __restrict__ h, const float* __restrict__ ef, const float* __restrict__ norm,
    const int* __restrict__ src, const int* __restrict__ dst,
    float* __restrict__ asum, float* __restrict__ asq,
    unsigned* __restrict__ aumax, unsigned* __restrict__ aumin,
    int* __restrict__ deg, int E) {
  int lane = threadIdx.x & 63;
  int sub = lane >> 4;
  int f0 = (lane & 15) << 2;
  int wid = blockIdx.x * (blockDim.x >> 6) + (threadIdx.x >> 6);
  int nw = gridDim.x * (blockDim.x >> 6);
  for (int ebase = wid * 4; ebase < E; ebase += nw * 4) {
    int e = ebase + sub;
    if (e >= E) continue;
    int s = src[e];
    int d = dst[e];
    float ns = norm[s];
    float4 hv = *(const float4*)&h[(size_t)s * 64 + f0];
    float4 ev = *(const float4*)&ef[(size_t)e * 64 + f0];
    float w0 = hv.x * ns + ev.x;
    float w1 = hv.y * ns + ev.y;
    float w2 = hv.z * ns + ev.z;
    float w3 = hv.w * ns + ev.w;
    size_t base = (size_t)d * 64 + f0;
    unsafeAtomicAdd(&asum[base + 0], w0);
    unsafeAtomicAdd(&asum[base + 1], w1);
    unsafeAtomicAdd(&asum[base + 2], w2);
    unsafeAtomicAdd(&asum[base + 3], w3);
    unsafeAtomicAdd(&asq[base + 0], w0 * w0);
    unsafeAtomicAdd(&asq[base + 1], w1 * w1);
    unsafeAtomicAdd(&asq[base + 2], w2 * w2);
    unsafeAtomicAdd(&asq[base + 3], w3 * w3);
    atomicMax(&aumax[base + 0], enc(w0));
    atomicMax(&aumax[base + 1], enc(w1));
    atomicMax(&aumax[base + 2], enc(w2));
    atomicMax(&aumax[base + 3], enc(w3));
    atomicMin(&aumin[base + 0], enc(w0));
    atomicMin(&aumin[base + 1], enc(w1));
    atomicMin(&aumin[base + 2], enc(w2));
    atomicMin(&aumin[base + 3], enc(w3));
    if ((lane & 15) == 0) atomicAdd(&deg[d], 1);
  }
}

// ---------------- node kernel: finalize stats -> ht, accumulate BN1 column stats ----------------
__global__ __launch_bounds__(256) void k_node(
    const float* __restrict__ h, const float* __restrict__ norm,
    const float* __restrict__ asum, const float* __restrict__ asq,
    const unsigned* __restrict__ aumax, const unsigned* __restrict__ aumin,
    const int* __restrict__ deg, float* __restrict__ ht,
    double* __restrict__ gsum, double* __restrict__ gsq, int N) {
  int lane = threadIdx.x & 63;
  int sub = threadIdx.x >> 6;
  int row = blockIdx.x * 4 + sub;
  int stride = gridDim.x * 4;
  double s = 0.0, q = 0.0;
  for (; row < N; row += stride) {
    size_t base = (size_t)row * 64 + lane;
    float dg = (float)deg[row];
    float hd = h[base] * norm[row];         // h_in[dst] (the constant shift)
    float sw = asum[base];
    float qw = asq[base];
    float mw = sw / dg;
    float mean = mw + hd;
    float var = fmaxf(0.f, qw / dg - mw * mw);   // shift-invariant
    float sd = sqrtf(var + 1e-5f);
    float mx = dec(aumax[base]) + hd;
    float mn = dec(aumin[base]) + hd;
    float ld = logf(dg + 1.f);
    float scl = 1.f + ld * (1.f / AVGD) + AVGD / ld;
    float v = (hd + (mean + mx + mn + sd) * scl) * (1.f / 13.f);
    ht[base] = v;
    s += v;
    q += (double)v * (double)v;
  }
  __shared__ double ls[256], lq[256];
  ls[threadIdx.x] = s;
  lq[threadIdx.x] = q;
  __syncthreads();
  if (threadIdx.x < 64) {
    double ss = ls[threadIdx.x] + ls[threadIdx.x + 64] + ls[threadIdx.x + 128] + ls[threadIdx.x + 192];
    double qq = lq[threadIdx.x] + lq[threadIdx.x + 64] + lq[threadIdx.x + 128] + lq[threadIdx.x + 192];
    unsafeAtomicAdd(&gsum[lane], ss);
    unsafeAtomicAdd(&gsq[lane], qq);
  }
}

// fold BN (training-mode, biased var) into per-column scale/bias
__global__ void k_finalize(const double* __restrict__ gsum, const double* __restrict__ gsq,
                           const float* __restrict__ g, const float* __restrict__ b,
                           float* __restrict__ scale, float* __restrict__ bias, int N) {
  int d = threadIdx.x;
  if (d >= 64) return;
  double m = gsum[d] / (double)N;
  double v = gsq[d] / (double)N - m * m;
  if (v < 0.0) v = 0.0;
  double istd = 1.0 / sqrt(v + 1e-5);
  double sg = istd * (double)g[d];
  scale[d] = (float)sg;
  bias[d] = (float)((double)b[d] - m * sg);
}

// BN1 apply * norm -> relu -> write r, accumulate BN2 stats in same pass
__global__ __launch_bounds__(256) void k_bnrelu(
    const float* __restrict__ ht, const float* __restrict__ norm,
    const float* __restrict__ scale1, const float* __restrict__ bias1,
    float* __restrict__ r, double* __restrict__ gsum2, double* __restrict__ gsq2, int N) {
  int lane = threadIdx.x & 63;
  int sub = threadIdx.x >> 6;
  float sc = scale1[lane], bi = bias1[lane];
  int row = blockIdx.x * 4 + sub;
  int stride = gridDim.x * 4;
  double s = 0.0, q = 0.0;
  for (; row < N; row += stride) {
    float v = ht[(size_t)row * 64 + lane];
    float rv = fmaxf(0.f, (v * sc + bi) * norm[row]);
    r[(size_t)row * 64 + lane] = rv;
    s += rv;
    q += (double)rv * (double)rv;
  }
  __shared__ double ls[256], lq[256];
  ls[threadIdx.x] = s;
  lq[threadIdx.x] = q;
  __syncthreads();
  if (threadIdx.x < 64) {
    double ss = ls[threadIdx.x] + ls[threadIdx.x + 64] + ls[threadIdx.x + 128] + ls[threadIdx.x + 192];
    double qq = lq[threadIdx.x] + lq[threadIdx.x + 64] + lq[threadIdx.x + 128] + lq[threadIdx.x + 192];
    unsafeAtomicAdd(&gsum2[lane], ss);
    unsafeAtomicAdd(&gsq2[lane], qq);
  }
}

// final BN2 apply, float4 vectorized
__global__ void k_out(const float* __restrict__ r, const float* __restrict__ scale2,
                      const float* __restrict__ bias2, float* __restrict__ out, int total4) {
  int i = blockIdx.x * blockDim.x + threadIdx.x;
  if (i >= total4) return;
  float4 v = ((const float4*)r)[i];
  float4 sc = ((const float4*)scale2)[i & 15];
  float4 bb = ((const float4*)bias2)[i & 15];
  float4 o;
  o.x = v.x * sc.x + bb.x;
  o.y = v.y * sc.y + bb.y;
  o.z = v.z * sc.z + bb.z;
  o.w = v.w * sc.w + bb.w;
  ((float4*)out)[i] = o;
}

extern "C" void kernel_launch(void* const* d_in, const int* in_sizes, int n_in,
                              void* d_out, int out_size, void* d_ws, size_t ws_size,
                              hipStream_t stream) {
  const float* h = (const float*)d_in[0];
  const float* ef = (const float*)d_in[1];
  const float* norm = (const float*)d_in[2];
  const float* g1 = (const float*)d_in[3];
  const float* b1 = (const float*)d_in[4];
  const float* g2 = (const float*)d_in[5];
  const float* b2 = (const float*)d_in[6];
  const int* src = (const int*)d_in[7];
  const int* dst = (const int*)d_in[8];
  const int N = in_sizes[2];  // norm is [N,1]
  const int E = in_sizes[8];  // dst is [E]
  float* out = (float*)d_out;

  char* ws = (char*)d_ws;
  size_t o = 0;
  auto alloc = [&](size_t bytes) -> void* {
    void* p = ws + o;
    o += (bytes + 255) & ~(size_t)255;
    return p;
  };
  const size_t ND = (size_t)N * 64;
  // zero-init block: asum, asq, aumax, deg, gsums (contiguous, one memset)
  size_t zbeg = o;
  float* asum = (float*)alloc(ND * 4);
  float* asq = (float*)alloc(ND * 4);
  unsigned* aumax = (unsigned*)alloc(ND * 4);
  int* deg = (int*)alloc((size_t)N * 4);
  double* gsum1 = (double*)alloc(4 * 64 * 8);  // gsum1,gsq1,gsum2,gsq2
  double* gsq1 = gsum1 + 64;
  double* gsum2 = gsum1 + 128;
  double* gsq2 = gsum1 + 192;
  size_t zend = o;
  // 0xFF-init block: aumin (encoded +inf-most = all ones = smallest... 0xFFFFFFFF is the MAX
  // encoding; for min we need init = 0xFFFFFFFF which IS all-ones)
  unsigned* aumin = (unsigned*)alloc(ND * 4);
  size_t fend = o;
  float* ht = (float*)alloc(ND * 4);
  float* rbuf = (float*)alloc(ND * 4);
  float* sc1 = (float*)alloc(4 * 64 * 4);  // sc1,bi1,sc2,bi2
  float* bi1 = sc1 + 64;
  float* sc2 = sc1 + 128;
  float* bi2 = sc1 + 192;

  hipMemsetAsync(ws + zbeg, 0x00, zend - zbeg, stream);
  hipMemsetAsync(ws + (zend), 0xFF, fend - zend, stream);

  k_edge<<<4096, 256, 0, stream>>>(h, ef, norm, src, dst, asum, asq, aumax, aumin, deg, E);
  k_node<<<1024, 256, 0, stream>>>(h, norm, asum, asq, aumax, aumin, deg, ht, gsum1, gsq1, N);
  k_finalize<<<1, 64, 0, stream>>>(gsum1, gsq1, g1, b1, sc1, bi1, N);
  k_bnrelu<<<512, 256, 0, stream>>>(ht, norm, sc1, bi1, rbuf, gsum2, gsq2, N);
  k_finalize<<<1, 64, 0, stream>>>(gsum2, gsq2, g2, b2, sc2, bi2, N);
  k_out<<<(N * 16 + 255) / 256, 256, 0, stream>>>(rbuf, sc2, bi2, out, N * 16);
}